// Round 5
// baseline (228.974 us; speedup 1.0000x reference)
//
#include <hip/hip_runtime.h>
#include <stdint.h>

// ---------------- workspace layout (float elements) ----------------
//  [0..3]  w absmax bits   [4..7] w_sf   [8..11] b_sf
//  [16..33] head absmax bits (q/k/v * 6 heads)
//  [40..45] qh_sf [46..51] kh_sf [52..57] vh_sf
//  [64..69] sf [70..75] x0_int [76..81] bpoly [82..87] c_int
//  [88..93] exp_sf [94..99] s16 [100..105] 30*x0
#define WS_WT     1024                        // w16 frag-order: 4 mats * 147456 ushort
#define WS_BI     (1024 + 4*147456)           // 590848 (float b_int)
#define WS_QBUF   (WS_BI + 1536)              // 592384: qkv fp32 (3*NE); later ab + abplanes
#define NROW      8192
#define NE        (NROW*384)                  // 3145728
#define WS_C8     (WS_QBUF + 3*NE)            // xplanes (2*NE ushort) then q8/k8/vf
// total floats: WS_C8 + NE = 13,175,296 (~52.7 MB)

typedef __attribute__((ext_vector_type(4))) int      i32x4;
typedef __attribute__((ext_vector_type(4))) float    f32x4;
typedef __attribute__((ext_vector_type(8))) _Float16 f16x8;

__global__ __launch_bounds__(256) void k_init(float* ws) {
    ws[threadIdx.x] = 0.0f;      // zero ws[0..255]: all scalar/atomic slots
}

__device__ __forceinline__ float blockmax_and_get(float lmax, float* red) {
    #pragma unroll
    for (int off = 32; off; off >>= 1) lmax = fmaxf(lmax, __shfl_xor(lmax, off, 64));
    int wv = threadIdx.x >> 6, ln = threadIdx.x & 63;
    if (ln == 0) red[wv] = lmax;
    __syncthreads();
    return fmaxf(fmaxf(red[0], red[1]), fmaxf(red[2], red[3]));
}

__global__ __launch_bounds__(256) void k_wmax(const float* __restrict__ w0, const float* __restrict__ w1,
                                              const float* __restrict__ w2, const float* __restrict__ w3,
                                              float* ws) {
    int m = blockIdx.x / 36, chunk = blockIdx.x % 36;
    const float* w = (m == 0) ? w0 : (m == 1) ? w1 : (m == 2) ? w2 : w3;
    int base = chunk * 4096 + threadIdx.x;
    float lmax = 0.f;
    #pragma unroll
    for (int i = 0; i < 16; i++) lmax = fmaxf(lmax, fabsf(w[base + i*256]));
    __shared__ float red[4];
    float m4 = blockmax_and_get(lmax, red);
    if (threadIdx.x == 0) atomicMax((unsigned int*)&ws[m], __float_as_uint(m4));
}

// quantize weights -> f16 (exact, int8 range) in MFMA B-fragment order; biases fp32
__global__ __launch_bounds__(256) void k_wquant(const float* __restrict__ w0, const float* __restrict__ w1,
                                                const float* __restrict__ w2, const float* __restrict__ w3,
                                                const float* __restrict__ b0, const float* __restrict__ b1,
                                                const float* __restrict__ b2, const float* __restrict__ b3,
                                                const float* __restrict__ xsf, float* ws) {
    const unsigned* wu = (const unsigned*)ws;
    if (blockIdx.x < 576) {
        int m = blockIdx.x / 144, chunk = blockIdx.x % 144;
        const float* w = (m == 0) ? w0 : (m == 1) ? w1 : (m == 2) ? w2 : w3;
        float s = fmaxf(__uint_as_float(wu[m]), 1e-8f) / 127.0f;
        unsigned short* wt16 = (unsigned short*)(ws + WS_WT) + m * 147456;
        int base = chunk * 1024 + threadIdx.x;
        #pragma unroll
        for (int i = 0; i < 4; i++) {
            int e = base + i * 256;
            int o = e / 384, k = e - o * 384;
            float q = fminf(fmaxf(rintf(w[e] / s), -128.f), 127.f);
            _Float16 qh = (_Float16)q;
            unsigned short qb;
            __builtin_memcpy(&qb, &qh, 2);
            int idx = ((o >> 4) * 12 + (k >> 5)) * 512 + ((((k & 31) >> 3) << 4) + (o & 15)) * 8 + (k & 7);
            wt16[idx] = qb;
        }
    } else {
        for (int idx = threadIdx.x; idx < 1536; idx += 256) {
            int m = idx / 384, o = idx - m * 384;
            const float* b = (m == 0) ? b0 : (m == 1) ? b1 : (m == 2) ? b2 : b3;
            float s = fmaxf(__uint_as_float(wu[m]), 1e-8f) / 127.0f;
            float bsf = (m < 3) ? __fmul_rn(s, xsf[0]) : __fmul_rn(s, 0.00390625f);
            float bq = fminf(fmaxf(rintf(b[o] / bsf), -2147483648.0f), 2147483648.0f);
            ws[WS_BI + m * 384 + o] = bq;
            if (o == 0) { ws[4 + m] = s; ws[8 + m] = bsf; }
        }
    }
}

// fp32 -> exact f16 hi/lo planes in MFMA A-fragment order
template<bool DIV>
__global__ __launch_bounds__(256) void k_xsplit(const float* __restrict__ src,
                                                const float* __restrict__ xsf,
                                                unsigned short* __restrict__ hip_,
                                                unsigned short* __restrict__ lop_) {
    int gid = blockIdx.x * 256 + threadIdx.x;
    int e0 = gid * 4;
    int row = e0 / 384, k = e0 - row * 384;
    float xs = DIV ? xsf[0] : 1.0f;
    float4 v = *(const float4*)&src[e0];
    float f[4] = {v.x, v.y, v.z, v.w};
    unsigned short hb[4], lb[4];
    #pragma unroll
    for (int i = 0; i < 4; i++) {
        float xi = DIV ? (f[i] / xs) : f[i];
        _Float16 h = (_Float16)xi;
        float hf = (float)h;
        _Float16 l = (_Float16)__fsub_rn(xi, hf);
        __builtin_memcpy(&hb[i], &h, 2);
        __builtin_memcpy(&lb[i], &l, 2);
    }
    int base = ((row >> 4) * 12 + (k >> 5)) * 512 + ((((k & 31) >> 3) << 4) + (row & 15)) * 8 + (k & 7);
    uint2 hp = make_uint2((unsigned)hb[0] | ((unsigned)hb[1] << 16),
                          (unsigned)hb[2] | ((unsigned)hb[3] << 16));
    uint2 lp = make_uint2((unsigned)lb[0] | ((unsigned)lb[1] << 16),
                          (unsigned)lb[2] | ((unsigned)lb[3] << 16));
    *(uint2*)(hip_ + base) = hp;
    *(uint2*)(lop_ + base) = lp;
}

// barrier-free MFMA GEMM (round-3 proven structure, templated tile).
// wave tile = (RT*16) x (CT*16); block = 4 waves: (w&1) row strip, (w>>1) col strip.
template<int RT, int CT, bool QKV>
__global__ __launch_bounds__(256) void k_gemm16(const unsigned short* __restrict__ xhi,
                                                const unsigned short* __restrict__ xlo,
                                                const float* ws,
                                                float* __restrict__ out_base,
                                                float* ws_mut) {
    int mtile = blockIdx.x, nt = blockIdx.y;
    int mat = QKV ? (nt / 3) : 3;
    int cb  = QKV ? ((nt % 3) * 128) : (nt * 128);
    const unsigned short* w16 = (const unsigned short*)(ws + WS_WT) + mat * 147456;
    const float* bi = ws + WS_BI + mat * 384;
    float bsf = ws[8 + mat];
    float* out = QKV ? (out_base + mat * NE) : out_base;

    int tid = threadIdx.x, w = tid >> 6, lane = tid & 63;
    int rt0 = mtile * (RT * 2) + (w & 1) * RT;
    int ct0 = (cb + (w >> 1) * (CT * 16)) >> 4;

    const unsigned short* ah = xhi + rt0 * 6144 + lane * 8;
    const unsigned short* al = xlo + rt0 * 6144 + lane * 8;
    const unsigned short* bw = w16 + ct0 * 6144 + lane * 8;

    f32x4 acc[RT][CT] = {};
    for (int k32 = 0; k32 < 12; k32++) {
        f16x8 bf[CT];
        #pragma unroll
        for (int ct = 0; ct < CT; ct++)
            bf[ct] = *(const f16x8*)(bw + (ct * 12 + k32) * 512);
        #pragma unroll
        for (int rt = 0; rt < RT; rt++) {
            f16x8 hi = *(const f16x8*)(ah + (rt * 12 + k32) * 512);
            f16x8 lo = *(const f16x8*)(al + (rt * 12 + k32) * 512);
            #pragma unroll
            for (int ct = 0; ct < CT; ct++) {
                acc[rt][ct] = __builtin_amdgcn_mfma_f32_16x16x32_f16(lo, bf[ct], acc[rt][ct], 0, 0, 0);
                acc[rt][ct] = __builtin_amdgcn_mfma_f32_16x16x32_f16(hi, bf[ct], acc[rt][ct], 0, 0, 0);
            }
        }
    }

    int quad = lane >> 4, l15 = lane & 15;
    float lmax = 0.f;
    #pragma unroll
    for (int rt = 0; rt < RT; rt++) {
        #pragma unroll
        for (int r = 0; r < 4; r++) {
            int row = (rt0 + rt) * 16 + quad * 4 + r;
            #pragma unroll
            for (int ct = 0; ct < CT; ct++) {
                int col = (ct0 + ct) * 16 + l15;
                float v = __fmul_rn(__fadd_rn(acc[rt][ct][r], bi[col]), bsf);
                lmax = fmaxf(lmax, fabsf(v));
                out[row * 384 + col] = v;
            }
        }
    }
    if (QKV) {
        #pragma unroll
        for (int off = 32; off; off >>= 1) lmax = fmaxf(lmax, __shfl_xor(lmax, off, 64));
        if (lane == 0)
            atomicMax((unsigned int*)&ws_mut[16 + mat * 6 + (ct0 >> 2)], __float_as_uint(lmax));
    } else {
        if (mtile == 0 && nt == 0 && tid == 0) out[NE] = bsf;   // out_sf
    }
}

__global__ void k_scales(float* ws) {
    int h = threadIdx.x;
    if (h >= 6) return;
    const unsigned* wu = (const unsigned*)ws;
    float qsf = fmaxf(__uint_as_float(wu[16 + 0 * 6 + h]), 1e-8f) / 127.0f;
    float ksf = fmaxf(__uint_as_float(wu[16 + 1 * 6 + h]), 1e-8f) / 127.0f;
    float vsf = fmaxf(__uint_as_float(wu[16 + 2 * 6 + h]), 1e-8f) / 127.0f;
    float sf = __fmul_rn(ksf, qsf);
    const float X0f = -0.6931f;
    const float C0f = 0.35815147f;
    const float C1f = (float)(0.96963238 / 0.35815147);
    const float C2f = (float)(1.0 / 0.35815147);
    float x0i   = floorf(X0f / sf);
    float bpoly = floorf(C1f / sf);
    float sfsq  = __fmul_rn(sf, sf);
    float cint  = floorf(C2f / sfsq);
    float psf   = __fmul_rn(C0f, sfsq);
    float expsf = psf / 1073741824.0f;
    float rawmax = __fmul_rn(cint, 1073741824.0f);
    float s16 = fmaxf(__fmul_rn(rawmax, expsf), 1e-8f) / 32767.0f;
    float thirty = __fmul_rn(30.0f, x0i);
    ws[40+h]=qsf; ws[46+h]=ksf; ws[52+h]=vsf; ws[64+h]=sf; ws[70+h]=x0i;
    ws[76+h]=bpoly; ws[82+h]=cint; ws[88+h]=expsf; ws[94+h]=s16; ws[100+h]=thirty;
}

__device__ __forceinline__ unsigned short f16bits(float x) {
    _Float16 h = (_Float16)x;
    unsigned short u;
    __builtin_memcpy(&u, &h, 2);
    return u;
}

// quantize q/k -> int8 row-major; v -> f16 in B-fragment-swizzled order
__global__ __launch_bounds__(256) void k_prequant(const float* __restrict__ qb,
                                                  const float* __restrict__ kb,
                                                  const float* __restrict__ vb,
                                                  const float* __restrict__ ws,
                                                  char* __restrict__ q8,
                                                  char* __restrict__ k8,
                                                  unsigned short* __restrict__ vf) {
    int sec = blockIdx.x / 3072;
    int id = (blockIdx.x % 3072) * 256 + threadIdx.x;
    if (sec < 2) {
        const float* src = sec ? kb : qb;
        const float* sfb = ws + (sec ? 46 : 40);
        int row = id / 96, c4 = (id % 96) * 4;
        float s = sfb[c4 >> 6];
        float4 v = *(const float4*)&src[row * 384 + c4];
        int a0 = (int)fminf(fmaxf(rintf(v.x / s), -128.f), 127.f);
        int a1 = (int)fminf(fmaxf(rintf(v.y / s), -128.f), 127.f);
        int a2 = (int)fminf(fmaxf(rintf(v.z / s), -128.f), 127.f);
        int a3 = (int)fminf(fmaxf(rintf(v.w / s), -128.f), 127.f);
        unsigned pk = (unsigned)(a0 & 255) | ((unsigned)(a1 & 255) << 8) |
                      ((unsigned)(a2 & 255) << 16) | ((unsigned)(a3 & 255) << 24);
        ((unsigned*)(sec ? k8 : q8))[id] = pk;
    } else {
        int d = id & 63;
        int rest = id >> 6;
        int kvg = rest & 63;
        int bh = rest >> 6;
        int b = bh / 6, h = bh - (bh / 6) * 6;
        float s = ws[52 + h];
        int kv0 = kvg * 4;
        unsigned pk01, pk23;
        {
            float v0 = vb[(b * 256 + kv0 + 0) * 384 + h * 64 + d];
            float v1 = vb[(b * 256 + kv0 + 1) * 384 + h * 64 + d];
            float v2 = vb[(b * 256 + kv0 + 2) * 384 + h * 64 + d];
            float v3 = vb[(b * 256 + kv0 + 3) * 384 + h * 64 + d];
            unsigned short u0 = f16bits(fminf(fmaxf(rintf(v0 / s), -128.f), 127.f));
            unsigned short u1 = f16bits(fminf(fmaxf(rintf(v1 / s), -128.f), 127.f));
            unsigned short u2 = f16bits(fminf(fmaxf(rintf(v2 / s), -128.f), 127.f));
            unsigned short u3 = f16bits(fminf(fmaxf(rintf(v3 / s), -128.f), 127.f));
            pk01 = (unsigned)u0 | ((unsigned)u1 << 16);
            pk23 = (unsigned)u2 | ((unsigned)u3 << 16);
        }
        int c = kv0 >> 5, quad = (kv0 >> 3) & 3, j0 = kv0 & 7;
        int base = ((bh * 8 + c) * 4 + (d >> 4)) * 512 + (quad * 16 + (d & 15)) * 8 + j0;
        uint2 pk = make_uint2(pk01, pk23);
        *(uint2*)&vf[base] = pk;
    }
}

// fused MFMA attention
__global__ __launch_bounds__(256) void k_attn(const char* __restrict__ q8,
                                              const char* __restrict__ k8,
                                              const unsigned short* __restrict__ vf,
                                              const float* __restrict__ ws,
                                              float* __restrict__ ab) {
    __shared__ _Float16 pS[4][64][8];
    int qt = blockIdx.x & 3, bh = blockIdx.x >> 2;
    int b = bh / 6, h = bh - (bh / 6) * 6;
    float qsf = ws[40+h], ksf = ws[46+h], vsf = ws[52+h];
    float sf = ws[64+h], x0i = ws[70+h], bpoly = ws[76+h], cint = ws[82+h];
    float expsf = ws[88+h], s16 = ws[94+h], thirty = ws[100+h];

    int tid = threadIdx.x, w = tid >> 6, lane = tid & 63;
    int quad = lane >> 4, l15 = lane & 15;
    int strip0 = qt * 64 + w * 16;
    int ntiles = (strip0 >> 4) + 1;

    const i32x4 afrag = *(const i32x4*)(q8 + (b * 256 + strip0 + l15) * 384 + h * 64 + quad * 16);

    f32x4 xi[16];
    i32x4 zero4 = {0, 0, 0, 0};
    #pragma unroll
    for (int ct = 0; ct < 16; ct++) {
        if (ct < ntiles) {
            i32x4 bfrag = *(const i32x4*)(k8 + (b * 256 + ct * 16 + l15) * 384 + h * 64 + quad * 16);
            i32x4 c = __builtin_amdgcn_mfma_i32_16x16x64_i8(afrag, bfrag, zero4, 0, 0, 0);
            #pragma unroll
            for (int r = 0; r < 4; r++) {
                float wei = __fmul_rn(__fmul_rn(__fmul_rn((float)c[r], qsf), ksf), 0.125f);
                xi[ct][r] = wei / sf;
            }
        }
    }

    float NI = -__builtin_inff();
    f32x4 m = {NI, NI, NI, NI};
    #pragma unroll
    for (int ct = 0; ct < 16; ct++) {
        if (ct < ntiles) {
            bool last = (ct == ntiles - 1);
            #pragma unroll
            for (int r = 0; r < 4; r++)
                if (!last || (l15 <= quad * 4 + r)) m[r] = fmaxf(m[r], xi[ct][r]);
        }
    }
    #pragma unroll
    for (int o = 8; o; o >>= 1) {
        m.x = fmaxf(m.x, __shfl_xor(m.x, o));
        m.y = fmaxf(m.y, __shfl_xor(m.y, o));
        m.z = fmaxf(m.z, __shfl_xor(m.z, o));
        m.w = fmaxf(m.w, __shfl_xor(m.w, o));
    }

    f32x4 sum = {0.f, 0.f, 0.f, 0.f};
    #pragma unroll
    for (int ct = 0; ct < 16; ct++) {
        if (ct < ntiles) {
            bool last = (ct == ntiles - 1);
            #pragma unroll
            for (int r = 0; r < 4; r++) {
                float ei = 0.f;
                if (!last || (l15 <= quad * 4 + r)) {
                    float xsv = fmaxf(__fsub_rn(xi[ct][r], m[r]), thirty);
                    float qf = floorf(xsv / x0i);
                    float rr = __fsub_rn(xsv, __fmul_rn(x0i, qf));
                    float z = __fadd_rn(__fmul_rn(__fadd_rn(rr, bpoly), rr), cint);
                    float p2 = ldexpf(1.0f, 30 - (int)qf);
                    float eraw = fmaxf(floorf(__fmul_rn(z, p2)), 0.0f);
                    float esc = __fmul_rn(eraw, expsf);
                    float q16 = fminf(fmaxf(rintf(esc / s16), -32768.f), 32767.f);
                    float e = __fmul_rn(q16, s16);
                    ei = e / s16;
                }
                xi[ct][r] = ei;
                sum[r] += ei;
            }
        }
    }
    #pragma unroll
    for (int o = 8; o; o >>= 1) {
        sum.x += __shfl_xor(sum.x, o);
        sum.y += __shfl_xor(sum.y, o);
        sum.z += __shfl_xor(sum.z, o);
        sum.w += __shfl_xor(sum.w, o);
    }
    f32x4 fac;
    #pragma unroll
    for (int r = 0; r < 4; r++) fac[r] = floorf(4294967296.0f / sum[r]);

    #pragma unroll
    for (int ct = 0; ct < 16; ct++) {
        #pragma unroll
        for (int r = 0; r < 4; r++) {
            if (ct < ntiles)
                xi[ct][r] = floorf(__fmul_rn(__fmul_rn(xi[ct][r], fac[r]), 5.9604644775390625e-08f));
            else
                xi[ct][r] = 0.f;
        }
    }

    f32x4 o0 = {0,0,0,0}, o1 = {0,0,0,0}, o2 = {0,0,0,0}, o3 = {0,0,0,0};
    int nch = (ntiles + 1) >> 1;
    #pragma unroll
    for (int c = 0; c < 8; c++) {
        if (c < nch) {
            #pragma unroll
            for (int t2 = 0; t2 < 2; t2++) {
                int qd = t2 * 2 + (l15 >> 3);
                #pragma unroll
                for (int r = 0; r < 4; r++)
                    pS[w][qd * 16 + quad * 4 + r][l15 & 7] = (_Float16)xi[2 * c + t2][r];
            }
            f16x8 pa = *(f16x8*)&pS[w][lane][0];
            int vbase = ((bh * 8 + c) * 4) * 512 + lane * 8;
            f16x8 vb0 = *(const f16x8*)&vf[vbase];
            f16x8 vb1 = *(const f16x8*)&vf[vbase + 512];
            f16x8 vb2 = *(const f16x8*)&vf[vbase + 1024];
            f16x8 vb3 = *(const f16x8*)&vf[vbase + 1536];
            o0 = __builtin_amdgcn_mfma_f32_16x16x32_f16(pa, vb0, o0, 0, 0, 0);
            o1 = __builtin_amdgcn_mfma_f32_16x16x32_f16(pa, vb1, o1, 0, 0, 0);
            o2 = __builtin_amdgcn_mfma_f32_16x16x32_f16(pa, vb2, o2, 0, 0, 0);
            o3 = __builtin_amdgcn_mfma_f32_16x16x32_f16(pa, vb3, o3, 0, 0, 0);
        }
    }

    float* outp = ab + (b * 256 + strip0 + quad * 4) * 384 + h * 64 + l15;
    #pragma unroll
    for (int r = 0; r < 4; r++) {
        outp[r * 384 +  0] = __fmul_rn(__fmul_rn(o0[r], vsf), 0.00390625f);
        outp[r * 384 + 16] = __fmul_rn(__fmul_rn(o1[r], vsf), 0.00390625f);
        outp[r * 384 + 32] = __fmul_rn(__fmul_rn(o2[r], vsf), 0.00390625f);
        outp[r * 384 + 48] = __fmul_rn(__fmul_rn(o3[r], vsf), 0.00390625f);
    }
}

extern "C" void kernel_launch(void* const* d_in, const int* in_sizes, int n_in,
                              void* d_out, int out_size, void* d_ws, size_t ws_size,
                              hipStream_t stream) {
    const float* x   = (const float*)d_in[0];
    const float* xsf = (const float*)d_in[1];
    const float* Wq  = (const float*)d_in[2];
    const float* bq  = (const float*)d_in[3];
    const float* Wk  = (const float*)d_in[4];
    const float* bk  = (const float*)d_in[5];
    const float* Wv  = (const float*)d_in[6];
    const float* bv  = (const float*)d_in[7];
    const float* Wp  = (const float*)d_in[8];
    const float* bp  = (const float*)d_in[9];
    float* ws  = (float*)d_ws;
    float* out = (float*)d_out;
    float* qkv = ws + WS_QBUF;

    unsigned short* xhi = (unsigned short*)(ws + WS_C8);
    unsigned short* xlo = xhi + NE;
    char*  q8  = (char*)(ws + WS_C8);
    char*  k8  = q8 + NE;
    unsigned short* vfp = (unsigned short*)(k8 + NE);
    float* ab  = ws + WS_QBUF;
    unsigned short* abhi = (unsigned short*)(ws + WS_QBUF + NE);
    unsigned short* ablo = abhi + NE;

    k_init<<<1, 256, 0, stream>>>(ws);
    k_wmax<<<144, 256, 0, stream>>>(Wq, Wk, Wv, Wp, ws);
    k_wquant<<<577, 256, 0, stream>>>(Wq, Wk, Wv, Wp, bq, bk, bv, bp, xsf, ws);
    k_xsplit<true><<<3072, 256, 0, stream>>>(x, xsf, xhi, xlo);
    k_gemm16<2, 4, true><<<dim3(128, 9), 256, 0, stream>>>(xhi, xlo, ws, qkv, ws);
    k_scales<<<1, 64, 0, stream>>>(ws);
    k_prequant<<<9216, 256, 0, stream>>>(qkv, qkv + NE, qkv + 2 * NE, ws, q8, k8, vfp);
    k_attn<<<768, 256, 0, stream>>>(q8, k8, vfp, ws, ab);
    k_xsplit<false><<<3072, 256, 0, stream>>>(ab, xsf, abhi, ablo);
    k_gemm16<1, 4, false><<<dim3(256, 3), 256, 0, stream>>>(abhi, ablo, ws, out, ws);
}

// Round 6
// 199.834 us; speedup vs baseline: 1.1458x; 1.1458x over previous
//
#include <hip/hip_runtime.h>
#include <stdint.h>

// ---------------- workspace layout (float elements) ----------------
//  [0..3]  w absmax bits   [4..7] w_sf   [8..11] b_sf
//  [16..33] head absmax bits (q/k/v * 6 heads)
//  [40..45] qh_sf [46..51] kh_sf [52..57] vh_sf
//  [64..69] sf [70..75] x0_int [76..81] bpoly [82..87] c_int
//  [88..93] exp_sf [94..99] s16 [100..105] 30*x0
#define WS_WT     1024                        // w16 frag-order: 4 mats * 147456 ushort
#define WS_BI     (1024 + 4*147456)           // 590848 (float b_int)
#define WS_QBUF   (WS_BI + 1536)              // 592384: qkv fp32 (3*NE); later attn planes
#define NROW      8192
#define NE        (NROW*384)                  // 3145728
#define WS_C8     (WS_QBUF + 3*NE)            // xplanes (2*NE ushort) then q8/k8/vf
// total floats: WS_C8 + NE = 13,175,296 (~52.7 MB)

typedef __attribute__((ext_vector_type(4))) int      i32x4;
typedef __attribute__((ext_vector_type(4))) float    f32x4;
typedef __attribute__((ext_vector_type(8))) _Float16 f16x8;

__device__ __forceinline__ void gl2lds16(const void* g, void* l) {
    __builtin_amdgcn_global_load_lds(
        (const __attribute__((address_space(1))) unsigned*)g,
        (__attribute__((address_space(3))) unsigned*)l, 16, 0, 0);
}

__global__ __launch_bounds__(256) void k_init(float* ws) {
    ws[threadIdx.x] = 0.0f;
}

__device__ __forceinline__ float blockmax_and_get(float lmax, float* red) {
    #pragma unroll
    for (int off = 32; off; off >>= 1) lmax = fmaxf(lmax, __shfl_xor(lmax, off, 64));
    int wv = threadIdx.x >> 6, ln = threadIdx.x & 63;
    if (ln == 0) red[wv] = lmax;
    __syncthreads();
    return fmaxf(fmaxf(red[0], red[1]), fmaxf(red[2], red[3]));
}

__global__ __launch_bounds__(256) void k_wmax(const float* __restrict__ w0, const float* __restrict__ w1,
                                              const float* __restrict__ w2, const float* __restrict__ w3,
                                              float* ws) {
    int m = blockIdx.x / 36, chunk = blockIdx.x % 36;
    const float* w = (m == 0) ? w0 : (m == 1) ? w1 : (m == 2) ? w2 : w3;
    int base = chunk * 4096 + threadIdx.x;
    float lmax = 0.f;
    #pragma unroll
    for (int i = 0; i < 16; i++) lmax = fmaxf(lmax, fabsf(w[base + i*256]));
    __shared__ float red[4];
    float m4 = blockmax_and_get(lmax, red);
    if (threadIdx.x == 0) atomicMax((unsigned int*)&ws[m], __float_as_uint(m4));
}

// quantize weights -> f16 (exact, int8 range) in MFMA B-fragment order; biases fp32
__global__ __launch_bounds__(256) void k_wquant(const float* __restrict__ w0, const float* __restrict__ w1,
                                                const float* __restrict__ w2, const float* __restrict__ w3,
                                                const float* __restrict__ b0, const float* __restrict__ b1,
                                                const float* __restrict__ b2, const float* __restrict__ b3,
                                                const float* __restrict__ xsf, float* ws) {
    const unsigned* wu = (const unsigned*)ws;
    if (blockIdx.x < 576) {
        int m = blockIdx.x / 144, chunk = blockIdx.x % 144;
        const float* w = (m == 0) ? w0 : (m == 1) ? w1 : (m == 2) ? w2 : w3;
        float s = fmaxf(__uint_as_float(wu[m]), 1e-8f) / 127.0f;
        unsigned short* wt16 = (unsigned short*)(ws + WS_WT) + m * 147456;
        int base = chunk * 1024 + threadIdx.x;
        #pragma unroll
        for (int i = 0; i < 4; i++) {
            int e = base + i * 256;
            int o = e / 384, k = e - o * 384;
            float q = fminf(fmaxf(rintf(w[e] / s), -128.f), 127.f);
            _Float16 qh = (_Float16)q;
            unsigned short qb;
            __builtin_memcpy(&qb, &qh, 2);
            int idx = ((o >> 4) * 12 + (k >> 5)) * 512 + ((((k & 31) >> 3) << 4) + (o & 15)) * 8 + (k & 7);
            wt16[idx] = qb;
        }
    } else {
        for (int idx = threadIdx.x; idx < 1536; idx += 256) {
            int m = idx / 384, o = idx - m * 384;
            const float* b = (m == 0) ? b0 : (m == 1) ? b1 : (m == 2) ? b2 : b3;
            float s = fmaxf(__uint_as_float(wu[m]), 1e-8f) / 127.0f;
            float bsf = (m < 3) ? __fmul_rn(s, xsf[0]) : __fmul_rn(s, 0.00390625f);
            float bq = fminf(fmaxf(rintf(b[o] / bsf), -2147483648.0f), 2147483648.0f);
            ws[WS_BI + m * 384 + o] = bq;
            if (o == 0) { ws[4 + m] = s; ws[8 + m] = bsf; }
        }
    }
}

// fp32 -> exact f16 hi/lo planes in MFMA A-fragment order
__global__ __launch_bounds__(256) void k_xsplit(const float* __restrict__ src,
                                                const float* __restrict__ xsf,
                                                unsigned short* __restrict__ hip_,
                                                unsigned short* __restrict__ lop_) {
    int gid = blockIdx.x * 256 + threadIdx.x;
    int e0 = gid * 4;
    int row = e0 / 384, k = e0 - row * 384;
    float xs = xsf[0];
    float4 v = *(const float4*)&src[e0];
    float f[4] = {v.x, v.y, v.z, v.w};
    unsigned short hb[4], lb[4];
    #pragma unroll
    for (int i = 0; i < 4; i++) {
        float xi = f[i] / xs;
        _Float16 h = (_Float16)xi;
        float hf = (float)h;
        _Float16 l = (_Float16)__fsub_rn(xi, hf);
        __builtin_memcpy(&hb[i], &h, 2);
        __builtin_memcpy(&lb[i], &l, 2);
    }
    int base = ((row >> 4) * 12 + (k >> 5)) * 512 + ((((k & 31) >> 3) << 4) + (row & 15)) * 8 + (k & 7);
    uint2 hp = make_uint2((unsigned)hb[0] | ((unsigned)hb[1] << 16),
                          (unsigned)hb[2] | ((unsigned)hb[3] << 16));
    uint2 lp = make_uint2((unsigned)lb[0] | ((unsigned)lb[1] << 16),
                          (unsigned)lb[2] | ((unsigned)lb[3] << 16));
    *(uint2*)(hip_ + base) = hp;
    *(uint2*)(lop_ + base) = lp;
}

// m97-style LDS-staged MFMA GEMM: 128x128 block tile, 4 waves (64x64 each),
// BK=32, single-buffered 2-barrier K-loop, global_load_lds(16B) staging.
// Fragments are 1 KB contiguous in global (pre-swizzled), so one staging
// instruction moves exactly one 16x32 fragment; LDS dst = base + lane*16.
template<bool QKV>
__global__ __launch_bounds__(256) void k_gemm_lds(const unsigned short* __restrict__ xhi,
                                                  const unsigned short* __restrict__ xlo,
                                                  const float* ws,
                                                  float* __restrict__ out_base,
                                                  float* ws_mut) {
    __shared__ unsigned short smem[24 * 512];   // 24 KB: A-hi[8] A-lo[8] B[8] frags
    int mtile = blockIdx.x, nt = blockIdx.y;
    int mat = QKV ? (nt / 3) : 3;
    int cb  = QKV ? ((nt % 3) * 128) : (nt * 128);
    const unsigned short* w16 = (const unsigned short*)(ws + WS_WT) + mat * 147456;
    const float* bi = ws + WS_BI + mat * 384;
    float bsf = ws[8 + mat];
    float* out = QKV ? (out_base + mat * NE) : out_base;

    int tid = threadIdx.x, w = tid >> 6, lane = tid & 63;
    int rtg0 = mtile * 8;           // global 16-rowtile base (8 rowtiles/block)
    int ctg0 = cb >> 4;             // global 16-coltile base (8 coltiles/block)
    int rl0 = (w & 1) * 4, cl0 = (w >> 1) * 4;

    f32x4 acc[4][4] = {};
    for (int k = 0; k < 12; k++) {
        #pragma unroll
        for (int i = 0; i < 6; i++) {
            int f = w * 6 + i;      // wave-uniform fragment id
            const unsigned short* g;
            if (f < 8)       g = xhi + ((rtg0 + f) * 12 + k) * 512;
            else if (f < 16) g = xlo + ((rtg0 + f - 8) * 12 + k) * 512;
            else             g = w16 + ((ctg0 + f - 16) * 12 + k) * 512;
            gl2lds16(g + lane * 8, &smem[f * 512 + lane * 8]);
        }
        __syncthreads();            // compiler drains vmcnt before barrier
        f16x8 bf[4];
        #pragma unroll
        for (int ct = 0; ct < 4; ct++)
            bf[ct] = *(const f16x8*)&smem[(16 + cl0 + ct) * 512 + lane * 8];
        #pragma unroll
        for (int rt = 0; rt < 4; rt++) {
            f16x8 hi = *(const f16x8*)&smem[(rl0 + rt) * 512 + lane * 8];
            f16x8 lo = *(const f16x8*)&smem[(8 + rl0 + rt) * 512 + lane * 8];
            #pragma unroll
            for (int ct = 0; ct < 4; ct++) {
                acc[rt][ct] = __builtin_amdgcn_mfma_f32_16x16x32_f16(lo, bf[ct], acc[rt][ct], 0, 0, 0);
                acc[rt][ct] = __builtin_amdgcn_mfma_f32_16x16x32_f16(hi, bf[ct], acc[rt][ct], 0, 0, 0);
            }
        }
        __syncthreads();
    }

    int quad = lane >> 4, l15 = lane & 15;
    float lmax = 0.f;
    #pragma unroll
    for (int rt = 0; rt < 4; rt++) {
        #pragma unroll
        for (int r = 0; r < 4; r++) {
            int row = (rtg0 + rl0 + rt) * 16 + quad * 4 + r;
            #pragma unroll
            for (int ct = 0; ct < 4; ct++) {
                int col = (ctg0 + cl0 + ct) * 16 + l15;
                float v = __fmul_rn(__fadd_rn(acc[rt][ct][r], bi[col]), bsf);
                lmax = fmaxf(lmax, fabsf(v));
                out[row * 384 + col] = v;
            }
        }
    }
    if (QKV) {
        #pragma unroll
        for (int off = 32; off; off >>= 1) lmax = fmaxf(lmax, __shfl_xor(lmax, off, 64));
        int hd = (cb >> 6) + (w >> 1);   // wave's 64 cols = one head
        if (lane == 0)
            atomicMax((unsigned int*)&ws_mut[16 + mat * 6 + hd], __float_as_uint(lmax));
    } else {
        if (mtile == 0 && nt == 0 && tid == 0) out[NE] = bsf;   // out_sf
    }
}

__global__ void k_scales(float* ws) {
    int h = threadIdx.x;
    if (h >= 6) return;
    const unsigned* wu = (const unsigned*)ws;
    float qsf = fmaxf(__uint_as_float(wu[16 + 0 * 6 + h]), 1e-8f) / 127.0f;
    float ksf = fmaxf(__uint_as_float(wu[16 + 1 * 6 + h]), 1e-8f) / 127.0f;
    float vsf = fmaxf(__uint_as_float(wu[16 + 2 * 6 + h]), 1e-8f) / 127.0f;
    float sf = __fmul_rn(ksf, qsf);
    const float X0f = -0.6931f;
    const float C0f = 0.35815147f;
    const float C1f = (float)(0.96963238 / 0.35815147);
    const float C2f = (float)(1.0 / 0.35815147);
    float x0i   = floorf(X0f / sf);
    float bpoly = floorf(C1f / sf);
    float sfsq  = __fmul_rn(sf, sf);
    float cint  = floorf(C2f / sfsq);
    float psf   = __fmul_rn(C0f, sfsq);
    float expsf = psf / 1073741824.0f;
    float rawmax = __fmul_rn(cint, 1073741824.0f);
    float s16 = fmaxf(__fmul_rn(rawmax, expsf), 1e-8f) / 32767.0f;
    float thirty = __fmul_rn(30.0f, x0i);
    ws[40+h]=qsf; ws[46+h]=ksf; ws[52+h]=vsf; ws[64+h]=sf; ws[70+h]=x0i;
    ws[76+h]=bpoly; ws[82+h]=cint; ws[88+h]=expsf; ws[94+h]=s16; ws[100+h]=thirty;
}

__device__ __forceinline__ unsigned short f16bits(float x) {
    _Float16 h = (_Float16)x;
    unsigned short u;
    __builtin_memcpy(&u, &h, 2);
    return u;
}

// quantize q/k -> int8 row-major; v -> f16 in B-fragment-swizzled order
__global__ __launch_bounds__(256) void k_prequant(const float* __restrict__ qb,
                                                  const float* __restrict__ kb,
                                                  const float* __restrict__ vb,
                                                  const float* __restrict__ ws,
                                                  char* __restrict__ q8,
                                                  char* __restrict__ k8,
                                                  unsigned short* __restrict__ vf) {
    int sec = blockIdx.x / 3072;
    int id = (blockIdx.x % 3072) * 256 + threadIdx.x;
    if (sec < 2) {
        const float* src = sec ? kb : qb;
        const float* sfb = ws + (sec ? 46 : 40);
        int row = id / 96, c4 = (id % 96) * 4;
        float s = sfb[c4 >> 6];
        float4 v = *(const float4*)&src[row * 384 + c4];
        int a0 = (int)fminf(fmaxf(rintf(v.x / s), -128.f), 127.f);
        int a1 = (int)fminf(fmaxf(rintf(v.y / s), -128.f), 127.f);
        int a2 = (int)fminf(fmaxf(rintf(v.z / s), -128.f), 127.f);
        int a3 = (int)fminf(fmaxf(rintf(v.w / s), -128.f), 127.f);
        unsigned pk = (unsigned)(a0 & 255) | ((unsigned)(a1 & 255) << 8) |
                      ((unsigned)(a2 & 255) << 16) | ((unsigned)(a3 & 255) << 24);
        ((unsigned*)(sec ? k8 : q8))[id] = pk;
    } else {
        int d = id & 63;
        int rest = id >> 6;
        int kvg = rest & 63;
        int bh = rest >> 6;
        int b = bh / 6, h = bh - (bh / 6) * 6;
        float s = ws[52 + h];
        int kv0 = kvg * 4;
        unsigned pk01, pk23;
        {
            float v0 = vb[(b * 256 + kv0 + 0) * 384 + h * 64 + d];
            float v1 = vb[(b * 256 + kv0 + 1) * 384 + h * 64 + d];
            float v2 = vb[(b * 256 + kv0 + 2) * 384 + h * 64 + d];
            float v3 = vb[(b * 256 + kv0 + 3) * 384 + h * 64 + d];
            unsigned short u0 = f16bits(fminf(fmaxf(rintf(v0 / s), -128.f), 127.f));
            unsigned short u1 = f16bits(fminf(fmaxf(rintf(v1 / s), -128.f), 127.f));
            unsigned short u2 = f16bits(fminf(fmaxf(rintf(v2 / s), -128.f), 127.f));
            unsigned short u3 = f16bits(fminf(fmaxf(rintf(v3 / s), -128.f), 127.f));
            pk01 = (unsigned)u0 | ((unsigned)u1 << 16);
            pk23 = (unsigned)u2 | ((unsigned)u3 << 16);
        }
        int c = kv0 >> 5, quad = (kv0 >> 3) & 3, j0 = kv0 & 7;
        int base = ((bh * 8 + c) * 4 + (d >> 4)) * 512 + (quad * 16 + (d & 15)) * 8 + j0;
        uint2 pk = make_uint2(pk01, pk23);
        *(uint2*)&vf[base] = pk;
    }
}

// fused MFMA attention; epilogue writes hi/lo f16 planes (A-fragment order)
// for the final GEMM directly (fused former k_xsplit<false>).
__global__ __launch_bounds__(256) void k_attn(const char* __restrict__ q8,
                                              const char* __restrict__ k8,
                                              const unsigned short* __restrict__ vf,
                                              const float* __restrict__ ws,
                                              unsigned short* __restrict__ abhi,
                                              unsigned short* __restrict__ ablo) {
    __shared__ _Float16 pS[4][64][8];
    int qt = blockIdx.x & 3, bh = blockIdx.x >> 2;
    int b = bh / 6, h = bh - (bh / 6) * 6;
    float qsf = ws[40+h], ksf = ws[46+h], vsf = ws[52+h];
    float sf = ws[64+h], x0i = ws[70+h], bpoly = ws[76+h], cint = ws[82+h];
    float expsf = ws[88+h], s16 = ws[94+h], thirty = ws[100+h];

    int tid = threadIdx.x, w = tid >> 6, lane = tid & 63;
    int quad = lane >> 4, l15 = lane & 15;
    int strip0 = qt * 64 + w * 16;
    int ntiles = (strip0 >> 4) + 1;

    const i32x4 afrag = *(const i32x4*)(q8 + (b * 256 + strip0 + l15) * 384 + h * 64 + quad * 16);

    f32x4 xi[16];
    i32x4 zero4 = {0, 0, 0, 0};
    #pragma unroll
    for (int ct = 0; ct < 16; ct++) {
        if (ct < ntiles) {
            i32x4 bfrag = *(const i32x4*)(k8 + (b * 256 + ct * 16 + l15) * 384 + h * 64 + quad * 16);
            i32x4 c = __builtin_amdgcn_mfma_i32_16x16x64_i8(afrag, bfrag, zero4, 0, 0, 0);
            #pragma unroll
            for (int r = 0; r < 4; r++) {
                float wei = __fmul_rn(__fmul_rn(__fmul_rn((float)c[r], qsf), ksf), 0.125f);
                xi[ct][r] = wei / sf;
            }
        }
    }

    float NI = -__builtin_inff();
    f32x4 m = {NI, NI, NI, NI};
    #pragma unroll
    for (int ct = 0; ct < 16; ct++) {
        if (ct < ntiles) {
            bool last = (ct == ntiles - 1);
            #pragma unroll
            for (int r = 0; r < 4; r++)
                if (!last || (l15 <= quad * 4 + r)) m[r] = fmaxf(m[r], xi[ct][r]);
        }
    }
    #pragma unroll
    for (int o = 8; o; o >>= 1) {
        m.x = fmaxf(m.x, __shfl_xor(m.x, o));
        m.y = fmaxf(m.y, __shfl_xor(m.y, o));
        m.z = fmaxf(m.z, __shfl_xor(m.z, o));
        m.w = fmaxf(m.w, __shfl_xor(m.w, o));
    }

    f32x4 sum = {0.f, 0.f, 0.f, 0.f};
    #pragma unroll
    for (int ct = 0; ct < 16; ct++) {
        if (ct < ntiles) {
            bool last = (ct == ntiles - 1);
            #pragma unroll
            for (int r = 0; r < 4; r++) {
                float ei = 0.f;
                if (!last || (l15 <= quad * 4 + r)) {
                    float xsv = fmaxf(__fsub_rn(xi[ct][r], m[r]), thirty);
                    float qf = floorf(xsv / x0i);
                    float rr = __fsub_rn(xsv, __fmul_rn(x0i, qf));
                    float z = __fadd_rn(__fmul_rn(__fadd_rn(rr, bpoly), rr), cint);
                    float p2 = ldexpf(1.0f, 30 - (int)qf);
                    float eraw = fmaxf(floorf(__fmul_rn(z, p2)), 0.0f);
                    float esc = __fmul_rn(eraw, expsf);
                    float q16 = fminf(fmaxf(rintf(esc / s16), -32768.f), 32767.f);
                    float e = __fmul_rn(q16, s16);
                    ei = e / s16;
                }
                xi[ct][r] = ei;
                sum[r] += ei;
            }
        }
    }
    #pragma unroll
    for (int o = 8; o; o >>= 1) {
        sum.x += __shfl_xor(sum.x, o);
        sum.y += __shfl_xor(sum.y, o);
        sum.z += __shfl_xor(sum.z, o);
        sum.w += __shfl_xor(sum.w, o);
    }
    f32x4 fac;
    #pragma unroll
    for (int r = 0; r < 4; r++) fac[r] = floorf(4294967296.0f / sum[r]);

    #pragma unroll
    for (int ct = 0; ct < 16; ct++) {
        #pragma unroll
        for (int r = 0; r < 4; r++) {
            if (ct < ntiles)
                xi[ct][r] = floorf(__fmul_rn(__fmul_rn(xi[ct][r], fac[r]), 5.9604644775390625e-08f));
            else
                xi[ct][r] = 0.f;
        }
    }

    f32x4 o[4] = {};
    int nch = (ntiles + 1) >> 1;
    #pragma unroll
    for (int c = 0; c < 8; c++) {
        if (c < nch) {
            #pragma unroll
            for (int t2 = 0; t2 < 2; t2++) {
                int qd = t2 * 2 + (l15 >> 3);
                #pragma unroll
                for (int r = 0; r < 4; r++)
                    pS[w][qd * 16 + quad * 4 + r][l15 & 7] = (_Float16)xi[2 * c + t2][r];
            }
            f16x8 pa = *(f16x8*)&pS[w][lane][0];
            int vbase = ((bh * 8 + c) * 4) * 512 + lane * 8;
            #pragma unroll
            for (int cc = 0; cc < 4; cc++) {
                f16x8 vbf = *(const f16x8*)&vf[vbase + cc * 512];
                o[cc] = __builtin_amdgcn_mfma_f32_16x16x32_f16(pa, vbf, o[cc], 0, 0, 0);
            }
        }
    }

    // epilogue: out = ipv*vsf/256, split to f16 hi/lo planes in A-frag order
    // element (row = b*256+strip0+quad*4+r, col = h*64 + cc*16 + l15)
    int rowt12 = ((b * 256 + strip0) >> 4) * 12;
    #pragma unroll
    for (int cc = 0; cc < 4; cc++) {
        int fb = (rowt12 + h * 2 + (cc >> 1)) * 512;
        int sub = ((cc & 1) * 2 + (l15 >> 3)) * 16;
        #pragma unroll
        for (int r = 0; r < 4; r++) {
            float v = __fmul_rn(__fmul_rn(o[cc][r], vsf), 0.00390625f);
            _Float16 hh = (_Float16)v;
            float hf = (float)hh;
            _Float16 ll = (_Float16)__fsub_rn(v, hf);
            unsigned short hbb, lbb;
            __builtin_memcpy(&hbb, &hh, 2);
            __builtin_memcpy(&lbb, &ll, 2);
            int idx = fb + (sub + quad * 4 + r) * 8 + (l15 & 7);
            abhi[idx] = hbb;
            ablo[idx] = lbb;
        }
    }
}

extern "C" void kernel_launch(void* const* d_in, const int* in_sizes, int n_in,
                              void* d_out, int out_size, void* d_ws, size_t ws_size,
                              hipStream_t stream) {
    const float* x   = (const float*)d_in[0];
    const float* xsf = (const float*)d_in[1];
    const float* Wq  = (const float*)d_in[2];
    const float* bq  = (const float*)d_in[3];
    const float* Wk  = (const float*)d_in[4];
    const float* bk  = (const float*)d_in[5];
    const float* Wv  = (const float*)d_in[6];
    const float* bv  = (const float*)d_in[7];
    const float* Wp  = (const float*)d_in[8];
    const float* bp  = (const float*)d_in[9];
    float* ws  = (float*)d_ws;
    float* out = (float*)d_out;
    float* qkv = ws + WS_QBUF;

    unsigned short* xhi = (unsigned short*)(ws + WS_C8);
    unsigned short* xlo = xhi + NE;
    char*  q8  = (char*)(ws + WS_C8);
    char*  k8  = q8 + NE;
    unsigned short* vfp = (unsigned short*)(k8 + NE);
    unsigned short* abhi = (unsigned short*)(ws + WS_QBUF + NE);  // dead k-region
    unsigned short* ablo = abhi + NE;

    k_init<<<1, 256, 0, stream>>>(ws);
    k_wmax<<<144, 256, 0, stream>>>(Wq, Wk, Wv, Wp, ws);
    k_wquant<<<577, 256, 0, stream>>>(Wq, Wk, Wv, Wp, bq, bk, bv, bp, xsf, ws);
    k_xsplit<<<3072, 256, 0, stream>>>(x, xsf, xhi, xlo);
    k_gemm_lds<true><<<dim3(64, 9), 256, 0, stream>>>(xhi, xlo, ws, qkv, ws);
    k_scales<<<1, 64, 0, stream>>>(ws);
    k_prequant<<<9216, 256, 0, stream>>>(qkv, qkv + NE, qkv + 2 * NE, ws, q8, k8, vfp);
    k_attn<<<768, 256, 0, stream>>>(q8, k8, vfp, ws, abhi, ablo);
    k_gemm_lds<false><<<dim3(64, 3), 256, 0, stream>>>(abhi, ablo, ws, out, ws);
}

// Round 7
// 199.592 us; speedup vs baseline: 1.1472x; 1.0012x over previous
//
#include <hip/hip_runtime.h>
#include <stdint.h>

// ---------------- workspace layout (float elements) ----------------
//  [0..3]  w absmax bits   [4..7] w_sf   [8..11] b_sf
//  [16..33] head absmax bits (q/k/v * 6 heads)
//  [40..45] qh_sf [46..51] kh_sf [52..57] vh_sf
//  [64..69] sf [70..75] x0_int [76..81] bpoly [82..87] c_int
//  [88..93] exp_sf [94..99] s16 [100..105] 30*x0
#define WS_WT     1024                        // w16 frag-order: 4 mats * 147456 ushort
#define WS_BI     (1024 + 4*147456)           // 590848 (float b_int)
#define WS_QBUF   (WS_BI + 1536)              // 592384: qkv fp32 (3*NE); later attn planes
#define NROW      8192
#define NE        (NROW*384)                  // 3145728
#define WS_C8     (WS_QBUF + 3*NE)            // xplanes (2*NE ushort) then q8/k8/vf
// total floats: WS_C8 + NE = 13,175,296 (~52.7 MB)

typedef __attribute__((ext_vector_type(4))) int      i32x4;
typedef __attribute__((ext_vector_type(4))) float    f32x4;
typedef __attribute__((ext_vector_type(8))) _Float16 f16x8;

// global -> LDS direct DMA, 16 B/lane. lds base MUST be wave-uniform:
// hardware writes lane i's 16 B at ldsbase + i*16 (guide m97/m104/m108).
__device__ __forceinline__ void gl2lds16(const void* g, void* lds_uniform) {
    __builtin_amdgcn_global_load_lds(
        (const __attribute__((address_space(1))) unsigned*)g,
        (__attribute__((address_space(3))) unsigned*)lds_uniform, 16, 0, 0);
}

__global__ __launch_bounds__(256) void k_init(float* ws) {
    ws[threadIdx.x] = 0.0f;
}

__device__ __forceinline__ float blockmax_and_get(float lmax, float* red) {
    #pragma unroll
    for (int off = 32; off; off >>= 1) lmax = fmaxf(lmax, __shfl_xor(lmax, off, 64));
    int wv = threadIdx.x >> 6, ln = threadIdx.x & 63;
    if (ln == 0) red[wv] = lmax;
    __syncthreads();
    return fmaxf(fmaxf(red[0], red[1]), fmaxf(red[2], red[3]));
}

__global__ __launch_bounds__(256) void k_wmax(const float* __restrict__ w0, const float* __restrict__ w1,
                                              const float* __restrict__ w2, const float* __restrict__ w3,
                                              float* ws) {
    int m = blockIdx.x / 36, chunk = blockIdx.x % 36;
    const float* w = (m == 0) ? w0 : (m == 1) ? w1 : (m == 2) ? w2 : w3;
    int base = chunk * 4096 + threadIdx.x;
    float lmax = 0.f;
    #pragma unroll
    for (int i = 0; i < 16; i++) lmax = fmaxf(lmax, fabsf(w[base + i*256]));
    __shared__ float red[4];
    float m4 = blockmax_and_get(lmax, red);
    if (threadIdx.x == 0) atomicMax((unsigned int*)&ws[m], __float_as_uint(m4));
}

// quantize weights -> f16 (exact, int8 range) in MFMA B-fragment order; biases fp32
__global__ __launch_bounds__(256) void k_wquant(const float* __restrict__ w0, const float* __restrict__ w1,
                                                const float* __restrict__ w2, const float* __restrict__ w3,
                                                const float* __restrict__ b0, const float* __restrict__ b1,
                                                const float* __restrict__ b2, const float* __restrict__ b3,
                                                const float* __restrict__ xsf, float* ws) {
    const unsigned* wu = (const unsigned*)ws;
    if (blockIdx.x < 576) {
        int m = blockIdx.x / 144, chunk = blockIdx.x % 144;
        const float* w = (m == 0) ? w0 : (m == 1) ? w1 : (m == 2) ? w2 : w3;
        float s = fmaxf(__uint_as_float(wu[m]), 1e-8f) / 127.0f;
        unsigned short* wt16 = (unsigned short*)(ws + WS_WT) + m * 147456;
        int base = chunk * 1024 + threadIdx.x;
        #pragma unroll
        for (int i = 0; i < 4; i++) {
            int e = base + i * 256;
            int o = e / 384, k = e - o * 384;
            float q = fminf(fmaxf(rintf(w[e] / s), -128.f), 127.f);
            _Float16 qh = (_Float16)q;
            unsigned short qb;
            __builtin_memcpy(&qb, &qh, 2);
            int idx = ((o >> 4) * 12 + (k >> 5)) * 512 + ((((k & 31) >> 3) << 4) + (o & 15)) * 8 + (k & 7);
            wt16[idx] = qb;
        }
    } else {
        for (int idx = threadIdx.x; idx < 1536; idx += 256) {
            int m = idx / 384, o = idx - m * 384;
            const float* b = (m == 0) ? b0 : (m == 1) ? b1 : (m == 2) ? b2 : b3;
            float s = fmaxf(__uint_as_float(wu[m]), 1e-8f) / 127.0f;
            float bsf = (m < 3) ? __fmul_rn(s, xsf[0]) : __fmul_rn(s, 0.00390625f);
            float bq = fminf(fmaxf(rintf(b[o] / bsf), -2147483648.0f), 2147483648.0f);
            ws[WS_BI + m * 384 + o] = bq;
            if (o == 0) { ws[4 + m] = s; ws[8 + m] = bsf; }
        }
    }
}

// fp32 -> exact f16 hi/lo planes in MFMA A-fragment order
__global__ __launch_bounds__(256) void k_xsplit(const float* __restrict__ src,
                                                const float* __restrict__ xsf,
                                                unsigned short* __restrict__ hip_,
                                                unsigned short* __restrict__ lop_) {
    int gid = blockIdx.x * 256 + threadIdx.x;
    int e0 = gid * 4;
    int row = e0 / 384, k = e0 - row * 384;
    float xs = xsf[0];
    float4 v = *(const float4*)&src[e0];
    float f[4] = {v.x, v.y, v.z, v.w};
    unsigned short hb[4], lb[4];
    #pragma unroll
    for (int i = 0; i < 4; i++) {
        float xi = f[i] / xs;
        _Float16 h = (_Float16)xi;
        float hf = (float)h;
        _Float16 l = (_Float16)__fsub_rn(xi, hf);
        __builtin_memcpy(&hb[i], &h, 2);
        __builtin_memcpy(&lb[i], &l, 2);
    }
    int base = ((row >> 4) * 12 + (k >> 5)) * 512 + ((((k & 31) >> 3) << 4) + (row & 15)) * 8 + (k & 7);
    uint2 hp = make_uint2((unsigned)hb[0] | ((unsigned)hb[1] << 16),
                          (unsigned)hb[2] | ((unsigned)hb[3] << 16));
    uint2 lp = make_uint2((unsigned)lb[0] | ((unsigned)lb[1] << 16),
                          (unsigned)lb[2] | ((unsigned)lb[3] << 16));
    *(uint2*)(hip_ + base) = hp;
    *(uint2*)(lop_ + base) = lp;
}

// m97-style LDS-staged MFMA GEMM: 128x128 block tile, 4 waves (64x64 each),
// BK=32, single-buffered 2-barrier K-loop, global_load_lds(16B) staging with
// wave-uniform LDS base (hardware scatters lane i -> base + i*16).
template<bool QKV>
__global__ __launch_bounds__(256) void k_gemm_lds(const unsigned short* __restrict__ xhi,
                                                  const unsigned short* __restrict__ xlo,
                                                  const float* ws,
                                                  float* __restrict__ out_base,
                                                  float* ws_mut) {
    __shared__ unsigned short smem[24 * 512];   // 24 KB: A-hi[8] A-lo[8] B[8] frags
    int mtile = blockIdx.x, nt = blockIdx.y;
    int mat = QKV ? (nt / 3) : 3;
    int cb  = QKV ? ((nt % 3) * 128) : (nt * 128);
    const unsigned short* w16 = (const unsigned short*)(ws + WS_WT) + mat * 147456;
    const float* bi = ws + WS_BI + mat * 384;
    float bsf = ws[8 + mat];
    float* out = QKV ? (out_base + mat * NE) : out_base;

    int tid = threadIdx.x, w = tid >> 6, lane = tid & 63;
    int rtg0 = mtile * 8;           // global 16-rowtile base (8 rowtiles/block)
    int ctg0 = cb >> 4;             // global 16-coltile base (8 coltiles/block)
    int rl0 = (w & 1) * 4, cl0 = (w >> 1) * 4;

    f32x4 acc[4][4] = {};
    for (int k = 0; k < 12; k++) {
        #pragma unroll
        for (int i = 0; i < 6; i++) {
            int f = w * 6 + i;      // wave-uniform fragment id
            const unsigned short* g;
            if (f < 8)       g = xhi + ((rtg0 + f) * 12 + k) * 512;
            else if (f < 16) g = xlo + ((rtg0 + f - 8) * 12 + k) * 512;
            else             g = w16 + ((ctg0 + f - 16) * 12 + k) * 512;
            gl2lds16(g + lane * 8, &smem[f * 512]);   // uniform LDS base!
        }
        __syncthreads();            // compiler drains vmcnt before barrier
        f16x8 bf[4];
        #pragma unroll
        for (int ct = 0; ct < 4; ct++)
            bf[ct] = *(const f16x8*)&smem[(16 + cl0 + ct) * 512 + lane * 8];
        #pragma unroll
        for (int rt = 0; rt < 4; rt++) {
            f16x8 hi = *(const f16x8*)&smem[(rl0 + rt) * 512 + lane * 8];
            f16x8 lo = *(const f16x8*)&smem[(8 + rl0 + rt) * 512 + lane * 8];
            #pragma unroll
            for (int ct = 0; ct < 4; ct++) {
                acc[rt][ct] = __builtin_amdgcn_mfma_f32_16x16x32_f16(lo, bf[ct], acc[rt][ct], 0, 0, 0);
                acc[rt][ct] = __builtin_amdgcn_mfma_f32_16x16x32_f16(hi, bf[ct], acc[rt][ct], 0, 0, 0);
            }
        }
        __syncthreads();
    }

    int quad = lane >> 4, l15 = lane & 15;
    float lmax = 0.f;
    #pragma unroll
    for (int rt = 0; rt < 4; rt++) {
        #pragma unroll
        for (int r = 0; r < 4; r++) {
            int row = (rtg0 + rl0 + rt) * 16 + quad * 4 + r;
            #pragma unroll
            for (int ct = 0; ct < 4; ct++) {
                int col = (ctg0 + cl0 + ct) * 16 + l15;
                float v = __fmul_rn(__fadd_rn(acc[rt][ct][r], bi[col]), bsf);
                lmax = fmaxf(lmax, fabsf(v));
                out[row * 384 + col] = v;
            }
        }
    }
    if (QKV) {
        #pragma unroll
        for (int off = 32; off; off >>= 1) lmax = fmaxf(lmax, __shfl_xor(lmax, off, 64));
        int hd = (cb >> 6) + (w >> 1);   // wave's 64 cols = one head
        if (lane == 0)
            atomicMax((unsigned int*)&ws_mut[16 + mat * 6 + hd], __float_as_uint(lmax));
    } else {
        if (mtile == 0 && nt == 0 && tid == 0) out[NE] = bsf;   // out_sf
    }
}

__global__ void k_scales(float* ws) {
    int h = threadIdx.x;
    if (h >= 6) return;
    const unsigned* wu = (const unsigned*)ws;
    float qsf = fmaxf(__uint_as_float(wu[16 + 0 * 6 + h]), 1e-8f) / 127.0f;
    float ksf = fmaxf(__uint_as_float(wu[16 + 1 * 6 + h]), 1e-8f) / 127.0f;
    float vsf = fmaxf(__uint_as_float(wu[16 + 2 * 6 + h]), 1e-8f) / 127.0f;
    float sf = __fmul_rn(ksf, qsf);
    const float X0f = -0.6931f;
    const float C0f = 0.35815147f;
    const float C1f = (float)(0.96963238 / 0.35815147);
    const float C2f = (float)(1.0 / 0.35815147);
    float x0i   = floorf(X0f / sf);
    float bpoly = floorf(C1f / sf);
    float sfsq  = __fmul_rn(sf, sf);
    float cint  = floorf(C2f / sfsq);
    float psf   = __fmul_rn(C0f, sfsq);
    float expsf = psf / 1073741824.0f;
    float rawmax = __fmul_rn(cint, 1073741824.0f);
    float s16 = fmaxf(__fmul_rn(rawmax, expsf), 1e-8f) / 32767.0f;
    float thirty = __fmul_rn(30.0f, x0i);
    ws[40+h]=qsf; ws[46+h]=ksf; ws[52+h]=vsf; ws[64+h]=sf; ws[70+h]=x0i;
    ws[76+h]=bpoly; ws[82+h]=cint; ws[88+h]=expsf; ws[94+h]=s16; ws[100+h]=thirty;
}

__device__ __forceinline__ unsigned short f16bits(float x) {
    _Float16 h = (_Float16)x;
    unsigned short u;
    __builtin_memcpy(&u, &h, 2);
    return u;
}

// quantize q/k -> int8 row-major; v -> f16 in B-fragment-swizzled order
__global__ __launch_bounds__(256) void k_prequant(const float* __restrict__ qb,
                                                  const float* __restrict__ kb,
                                                  const float* __restrict__ vb,
                                                  const float* __restrict__ ws,
                                                  char* __restrict__ q8,
                                                  char* __restrict__ k8,
                                                  unsigned short* __restrict__ vf) {
    int sec = blockIdx.x / 3072;
    int id = (blockIdx.x % 3072) * 256 + threadIdx.x;
    if (sec < 2) {
        const float* src = sec ? kb : qb;
        const float* sfb = ws + (sec ? 46 : 40);
        int row = id / 96, c4 = (id % 96) * 4;
        float s = sfb[c4 >> 6];
        float4 v = *(const float4*)&src[row * 384 + c4];
        int a0 = (int)fminf(fmaxf(rintf(v.x / s), -128.f), 127.f);
        int a1 = (int)fminf(fmaxf(rintf(v.y / s), -128.f), 127.f);
        int a2 = (int)fminf(fmaxf(rintf(v.z / s), -128.f), 127.f);
        int a3 = (int)fminf(fmaxf(rintf(v.w / s), -128.f), 127.f);
        unsigned pk = (unsigned)(a0 & 255) | ((unsigned)(a1 & 255) << 8) |
                      ((unsigned)(a2 & 255) << 16) | ((unsigned)(a3 & 255) << 24);
        ((unsigned*)(sec ? k8 : q8))[id] = pk;
    } else {
        int d = id & 63;
        int rest = id >> 6;
        int kvg = rest & 63;
        int bh = rest >> 6;
        int b = bh / 6, h = bh - (bh / 6) * 6;
        float s = ws[52 + h];
        int kv0 = kvg * 4;
        unsigned pk01, pk23;
        {
            float v0 = vb[(b * 256 + kv0 + 0) * 384 + h * 64 + d];
            float v1 = vb[(b * 256 + kv0 + 1) * 384 + h * 64 + d];
            float v2 = vb[(b * 256 + kv0 + 2) * 384 + h * 64 + d];
            float v3 = vb[(b * 256 + kv0 + 3) * 384 + h * 64 + d];
            unsigned short u0 = f16bits(fminf(fmaxf(rintf(v0 / s), -128.f), 127.f));
            unsigned short u1 = f16bits(fminf(fmaxf(rintf(v1 / s), -128.f), 127.f));
            unsigned short u2 = f16bits(fminf(fmaxf(rintf(v2 / s), -128.f), 127.f));
            unsigned short u3 = f16bits(fminf(fmaxf(rintf(v3 / s), -128.f), 127.f));
            pk01 = (unsigned)u0 | ((unsigned)u1 << 16);
            pk23 = (unsigned)u2 | ((unsigned)u3 << 16);
        }
        int c = kv0 >> 5, quad = (kv0 >> 3) & 3, j0 = kv0 & 7;
        int base = ((bh * 8 + c) * 4 + (d >> 4)) * 512 + (quad * 16 + (d & 15)) * 8 + j0;
        uint2 pk = make_uint2(pk01, pk23);
        *(uint2*)&vf[base] = pk;
    }
}

// fused MFMA attention; epilogue writes hi/lo f16 planes (A-fragment order)
__global__ __launch_bounds__(256) void k_attn(const char* __restrict__ q8,
                                              const char* __restrict__ k8,
                                              const unsigned short* __restrict__ vf,
                                              const float* __restrict__ ws,
                                              unsigned short* __restrict__ abhi,
                                              unsigned short* __restrict__ ablo) {
    __shared__ _Float16 pS[4][64][8];
    int qt = blockIdx.x & 3, bh = blockIdx.x >> 2;
    int b = bh / 6, h = bh - (bh / 6) * 6;
    float qsf = ws[40+h], ksf = ws[46+h], vsf = ws[52+h];
    float sf = ws[64+h], x0i = ws[70+h], bpoly = ws[76+h], cint = ws[82+h];
    float expsf = ws[88+h], s16 = ws[94+h], thirty = ws[100+h];

    int tid = threadIdx.x, w = tid >> 6, lane = tid & 63;
    int quad = lane >> 4, l15 = lane & 15;
    int strip0 = qt * 64 + w * 16;
    int ntiles = (strip0 >> 4) + 1;

    const i32x4 afrag = *(const i32x4*)(q8 + (b * 256 + strip0 + l15) * 384 + h * 64 + quad * 16);

    f32x4 xi[16];
    i32x4 zero4 = {0, 0, 0, 0};
    #pragma unroll
    for (int ct = 0; ct < 16; ct++) {
        if (ct < ntiles) {
            i32x4 bfrag = *(const i32x4*)(k8 + (b * 256 + ct * 16 + l15) * 384 + h * 64 + quad * 16);
            i32x4 c = __builtin_amdgcn_mfma_i32_16x16x64_i8(afrag, bfrag, zero4, 0, 0, 0);
            #pragma unroll
            for (int r = 0; r < 4; r++) {
                float wei = __fmul_rn(__fmul_rn(__fmul_rn((float)c[r], qsf), ksf), 0.125f);
                xi[ct][r] = wei / sf;
            }
        }
    }

    float NI = -__builtin_inff();
    f32x4 m = {NI, NI, NI, NI};
    #pragma unroll
    for (int ct = 0; ct < 16; ct++) {
        if (ct < ntiles) {
            bool last = (ct == ntiles - 1);
            #pragma unroll
            for (int r = 0; r < 4; r++)
                if (!last || (l15 <= quad * 4 + r)) m[r] = fmaxf(m[r], xi[ct][r]);
        }
    }
    #pragma unroll
    for (int o = 8; o; o >>= 1) {
        m.x = fmaxf(m.x, __shfl_xor(m.x, o));
        m.y = fmaxf(m.y, __shfl_xor(m.y, o));
        m.z = fmaxf(m.z, __shfl_xor(m.z, o));
        m.w = fmaxf(m.w, __shfl_xor(m.w, o));
    }

    f32x4 sum = {0.f, 0.f, 0.f, 0.f};
    #pragma unroll
    for (int ct = 0; ct < 16; ct++) {
        if (ct < ntiles) {
            bool last = (ct == ntiles - 1);
            #pragma unroll
            for (int r = 0; r < 4; r++) {
                float ei = 0.f;
                if (!last || (l15 <= quad * 4 + r)) {
                    float xsv = fmaxf(__fsub_rn(xi[ct][r], m[r]), thirty);
                    float qf = floorf(xsv / x0i);
                    float rr = __fsub_rn(xsv, __fmul_rn(x0i, qf));
                    float z = __fadd_rn(__fmul_rn(__fadd_rn(rr, bpoly), rr), cint);
                    float p2 = ldexpf(1.0f, 30 - (int)qf);
                    float eraw = fmaxf(floorf(__fmul_rn(z, p2)), 0.0f);
                    float esc = __fmul_rn(eraw, expsf);
                    float q16 = fminf(fmaxf(rintf(esc / s16), -32768.f), 32767.f);
                    float e = __fmul_rn(q16, s16);
                    ei = e / s16;
                }
                xi[ct][r] = ei;
                sum[r] += ei;
            }
        }
    }
    #pragma unroll
    for (int o = 8; o; o >>= 1) {
        sum.x += __shfl_xor(sum.x, o);
        sum.y += __shfl_xor(sum.y, o);
        sum.z += __shfl_xor(sum.z, o);
        sum.w += __shfl_xor(sum.w, o);
    }
    f32x4 fac;
    #pragma unroll
    for (int r = 0; r < 4; r++) fac[r] = floorf(4294967296.0f / sum[r]);

    #pragma unroll
    for (int ct = 0; ct < 16; ct++) {
        #pragma unroll
        for (int r = 0; r < 4; r++) {
            if (ct < ntiles)
                xi[ct][r] = floorf(__fmul_rn(__fmul_rn(xi[ct][r], fac[r]), 5.9604644775390625e-08f));
            else
                xi[ct][r] = 0.f;
        }
    }

    f32x4 o[4] = {};
    int nch = (ntiles + 1) >> 1;
    #pragma unroll
    for (int c = 0; c < 8; c++) {
        if (c < nch) {
            #pragma unroll
            for (int t2 = 0; t2 < 2; t2++) {
                int qd = t2 * 2 + (l15 >> 3);
                #pragma unroll
                for (int r = 0; r < 4; r++)
                    pS[w][qd * 16 + quad * 4 + r][l15 & 7] = (_Float16)xi[2 * c + t2][r];
            }
            f16x8 pa = *(f16x8*)&pS[w][lane][0];
            int vbase = ((bh * 8 + c) * 4) * 512 + lane * 8;
            #pragma unroll
            for (int cc = 0; cc < 4; cc++) {
                f16x8 vbf = *(const f16x8*)&vf[vbase + cc * 512];
                o[cc] = __builtin_amdgcn_mfma_f32_16x16x32_f16(pa, vbf, o[cc], 0, 0, 0);
            }
        }
    }

    // epilogue: out = ipv*vsf/256, split to f16 hi/lo planes in A-frag order
    int rowt12 = ((b * 256 + strip0) >> 4) * 12;
    #pragma unroll
    for (int cc = 0; cc < 4; cc++) {
        int fb = (rowt12 + h * 2 + (cc >> 1)) * 512;
        int sub = ((cc & 1) * 2 + (l15 >> 3)) * 16;
        #pragma unroll
        for (int r = 0; r < 4; r++) {
            float v = __fmul_rn(__fmul_rn(o[cc][r], vsf), 0.00390625f);
            _Float16 hh = (_Float16)v;
            float hf = (float)hh;
            _Float16 ll = (_Float16)__fsub_rn(v, hf);
            unsigned short hbb, lbb;
            __builtin_memcpy(&hbb, &hh, 2);
            __builtin_memcpy(&lbb, &ll, 2);
            int idx = fb + (sub + quad * 4 + r) * 8 + (l15 & 7);
            abhi[idx] = hbb;
            ablo[idx] = lbb;
        }
    }
}

extern "C" void kernel_launch(void* const* d_in, const int* in_sizes, int n_in,
                              void* d_out, int out_size, void* d_ws, size_t ws_size,
                              hipStream_t stream) {
    const float* x   = (const float*)d_in[0];
    const float* xsf = (const float*)d_in[1];
    const float* Wq  = (const float*)d_in[2];
    const float* bq  = (const float*)d_in[3];
    const float* Wk  = (const float*)d_in[4];
    const float* bk  = (const float*)d_in[5];
    const float* Wv  = (const float*)d_in[6];
    const float* bv  = (const float*)d_in[7];
    const float* Wp  = (const float*)d_in[8];
    const float* bp  = (const float*)d_in[9];
    float* ws  = (float*)d_ws;
    float* out = (float*)d_out;
    float* qkv = ws + WS_QBUF;

    unsigned short* xhi = (unsigned short*)(ws + WS_C8);
    unsigned short* xlo = xhi + NE;
    char*  q8  = (char*)(ws + WS_C8);
    char*  k8  = q8 + NE;
    unsigned short* vfp = (unsigned short*)(k8 + NE);
    unsigned short* abhi = (unsigned short*)(ws + WS_QBUF + NE);  // dead k-region
    unsigned short* ablo = abhi + NE;

    k_init<<<1, 256, 0, stream>>>(ws);
    k_wmax<<<144, 256, 0, stream>>>(Wq, Wk, Wv, Wp, ws);
    k_wquant<<<577, 256, 0, stream>>>(Wq, Wk, Wv, Wp, bq, bk, bv, bp, xsf, ws);
    k_xsplit<<<3072, 256, 0, stream>>>(x, xsf, xhi, xlo);
    k_gemm_lds<true><<<dim3(64, 9), 256, 0, stream>>>(xhi, xlo, ws, qkv, ws);
    k_scales<<<1, 64, 0, stream>>>(ws);
    k_prequant<<<9216, 256, 0, stream>>>(qkv, qkv + NE, qkv + 2 * NE, ws, q8, k8, vfp);
    k_attn<<<768, 256, 0, stream>>>(q8, k8, vfp, ws, abhi, ablo);
    k_gemm_lds<false><<<dim3(64, 3), 256, 0, stream>>>(abhi, ablo, ws, out, ws);
}

// Round 8
// 194.140 us; speedup vs baseline: 1.1794x; 1.0281x over previous
//
#include <hip/hip_runtime.h>
#include <stdint.h>

// ---------------- workspace layout (float elements) ----------------
//  [0..3]  w absmax bits   [4..7] w_sf   [8..11] b_sf
//  [16..33] head absmax bits (q/k/v * 6 heads)
//  [40..45] qh_sf [46..51] kh_sf [52..57] vh_sf
//  [64..69] sf [70..75] x0_int [76..81] bpoly [82..87] c_int
//  [88..93] exp_sf [94..99] s16 [100..105] 30*x0
#define WS_WT     1024                        // w16 frag-order: 4 mats * 147456 ushort
#define WS_BI     (1024 + 4*147456)           // 590848 (float b_int)
#define WS_QBUF   (WS_BI + 1536)              // 592384: qkv fp32 (3*NE); later attn planes
#define NROW      8192
#define NE        (NROW*384)                  // 3145728
#define WS_C8     (WS_QBUF + 3*NE)            // xplanes (2*NE ushort) then q8/k8/vf
// total floats: WS_C8 + NE = 13,175,296 (~52.7 MB)

typedef __attribute__((ext_vector_type(4))) int      i32x4;
typedef __attribute__((ext_vector_type(4))) float    f32x4;
typedef __attribute__((ext_vector_type(8))) _Float16 f16x8;

// global -> LDS direct DMA, 16 B/lane; lds base wave-uniform, lane i -> base+i*16
__device__ __forceinline__ void gl2lds16(const void* g, void* lds_uniform) {
    __builtin_amdgcn_global_load_lds(
        (const __attribute__((address_space(1))) unsigned*)g,
        (__attribute__((address_space(3))) unsigned*)lds_uniform, 16, 0, 0);
}

__global__ __launch_bounds__(256) void k_init(float* ws) {
    ws[threadIdx.x] = 0.0f;
}

__device__ __forceinline__ float blockmax_and_get(float lmax, float* red) {
    #pragma unroll
    for (int off = 32; off; off >>= 1) lmax = fmaxf(lmax, __shfl_xor(lmax, off, 64));
    int wv = threadIdx.x >> 6, ln = threadIdx.x & 63;
    if (ln == 0) red[wv] = lmax;
    __syncthreads();
    return fmaxf(fmaxf(red[0], red[1]), fmaxf(red[2], red[3]));
}

__global__ __launch_bounds__(256) void k_wmax(const float* __restrict__ w0, const float* __restrict__ w1,
                                              const float* __restrict__ w2, const float* __restrict__ w3,
                                              float* ws) {
    int m = blockIdx.x / 36, chunk = blockIdx.x % 36;
    const float* w = (m == 0) ? w0 : (m == 1) ? w1 : (m == 2) ? w2 : w3;
    int base = chunk * 4096 + threadIdx.x;
    float lmax = 0.f;
    #pragma unroll
    for (int i = 0; i < 16; i++) lmax = fmaxf(lmax, fabsf(w[base + i*256]));
    __shared__ float red[4];
    float m4 = blockmax_and_get(lmax, red);
    if (threadIdx.x == 0) atomicMax((unsigned int*)&ws[m], __float_as_uint(m4));
}

// quantize weights -> f16 (exact, int8 range) in MFMA B-fragment order; biases fp32
__global__ __launch_bounds__(256) void k_wquant(const float* __restrict__ w0, const float* __restrict__ w1,
                                                const float* __restrict__ w2, const float* __restrict__ w3,
                                                const float* __restrict__ b0, const float* __restrict__ b1,
                                                const float* __restrict__ b2, const float* __restrict__ b3,
                                                const float* __restrict__ xsf, float* ws) {
    const unsigned* wu = (const unsigned*)ws;
    if (blockIdx.x < 576) {
        int m = blockIdx.x / 144, chunk = blockIdx.x % 144;
        const float* w = (m == 0) ? w0 : (m == 1) ? w1 : (m == 2) ? w2 : w3;
        float s = fmaxf(__uint_as_float(wu[m]), 1e-8f) / 127.0f;
        unsigned short* wt16 = (unsigned short*)(ws + WS_WT) + m * 147456;
        int base = chunk * 1024 + threadIdx.x;
        #pragma unroll
        for (int i = 0; i < 4; i++) {
            int e = base + i * 256;
            int o = e / 384, k = e - o * 384;
            float q = fminf(fmaxf(rintf(w[e] / s), -128.f), 127.f);
            _Float16 qh = (_Float16)q;
            unsigned short qb;
            __builtin_memcpy(&qb, &qh, 2);
            int idx = ((o >> 4) * 12 + (k >> 5)) * 512 + ((((k & 31) >> 3) << 4) + (o & 15)) * 8 + (k & 7);
            wt16[idx] = qb;
        }
    } else {
        for (int idx = threadIdx.x; idx < 1536; idx += 256) {
            int m = idx / 384, o = idx - m * 384;
            const float* b = (m == 0) ? b0 : (m == 1) ? b1 : (m == 2) ? b2 : b3;
            float s = fmaxf(__uint_as_float(wu[m]), 1e-8f) / 127.0f;
            float bsf = (m < 3) ? __fmul_rn(s, xsf[0]) : __fmul_rn(s, 0.00390625f);
            float bq = fminf(fmaxf(rintf(b[o] / bsf), -2147483648.0f), 2147483648.0f);
            ws[WS_BI + m * 384 + o] = bq;
            if (o == 0) { ws[4 + m] = s; ws[8 + m] = bsf; }
        }
    }
}

// fp32 -> exact f16 hi/lo planes in MFMA A-fragment order
__global__ __launch_bounds__(256) void k_xsplit(const float* __restrict__ src,
                                                const float* __restrict__ xsf,
                                                unsigned short* __restrict__ hip_,
                                                unsigned short* __restrict__ lop_) {
    int gid = blockIdx.x * 256 + threadIdx.x;
    int e0 = gid * 4;
    int row = e0 / 384, k = e0 - row * 384;
    float xs = xsf[0];
    float4 v = *(const float4*)&src[e0];
    float f[4] = {v.x, v.y, v.z, v.w};
    unsigned short hb[4], lb[4];
    #pragma unroll
    for (int i = 0; i < 4; i++) {
        float xi = f[i] / xs;
        _Float16 h = (_Float16)xi;
        float hf = (float)h;
        _Float16 l = (_Float16)__fsub_rn(xi, hf);
        __builtin_memcpy(&hb[i], &h, 2);
        __builtin_memcpy(&lb[i], &l, 2);
    }
    int base = ((row >> 4) * 12 + (k >> 5)) * 512 + ((((k & 31) >> 3) << 4) + (row & 15)) * 8 + (k & 7);
    uint2 hp = make_uint2((unsigned)hb[0] | ((unsigned)hb[1] << 16),
                          (unsigned)hb[2] | ((unsigned)hb[3] << 16));
    uint2 lp = make_uint2((unsigned)lb[0] | ((unsigned)lb[1] << 16),
                          (unsigned)lb[2] | ((unsigned)lb[3] << 16));
    *(uint2*)(hip_ + base) = hp;
    *(uint2*)(lop_ + base) = lp;
}

// LDS-staged MFMA GEMM with double-buffered staging (one barrier per K-iter).
// Block tile = (RTB*16) x 128; 4 waves: (w&1) row half, (w>>1) col half.
// Buffer layout: frags [0..RTB)=A-hi, [RTB..2RTB)=A-lo, [2RTB..2RTB+8)=B.
template<int RTB, bool QKV>
__global__ __launch_bounds__(256) void k_gemm_lds(const unsigned short* __restrict__ xhi,
                                                  const unsigned short* __restrict__ xlo,
                                                  const float* ws,
                                                  float* __restrict__ out_base,
                                                  float* ws_mut) {
    constexpr int NF = 2 * RTB + 8;          // fragments per buffer
    constexpr int RT = RTB / 2;              // rowtiles per wave
    __shared__ unsigned short smem[2][NF * 512];
    int mtile = blockIdx.x, nt = blockIdx.y;
    int mat = QKV ? (nt / 3) : 3;
    int cb  = QKV ? ((nt % 3) * 128) : (nt * 128);
    const unsigned short* w16 = (const unsigned short*)(ws + WS_WT) + mat * 147456;
    const float* bi = ws + WS_BI + mat * 384;
    float bsf = ws[8 + mat];
    float* out = QKV ? (out_base + mat * NE) : out_base;

    int tid = threadIdx.x, w = tid >> 6, lane = tid & 63;
    int rtg0 = mtile * RTB;
    int ctg0 = cb >> 4;
    int rl0 = (w & 1) * RT, cl0 = (w >> 1) * 4;

    // stage fragment set for K-chunk k into buffer buf (wave-split, uniform ids)
    auto stage = [&](int buf, int k) {
        #pragma unroll
        for (int i = 0; i < NF / 4; i++) {
            int f = w * (NF / 4) + i;
            const unsigned short* g;
            if (f < RTB)           g = xhi + ((rtg0 + f) * 12 + k) * 512;
            else if (f < 2 * RTB)  g = xlo + ((rtg0 + f - RTB) * 12 + k) * 512;
            else                   g = w16 + ((ctg0 + f - 2 * RTB) * 12 + k) * 512;
            gl2lds16(g + lane * 8, &smem[buf][f * 512]);
        }
    };

    f32x4 acc[RT][4] = {};
    stage(0, 0);
    __syncthreads();
    for (int k = 0; k < 12; k++) {
        if (k < 11) stage((k + 1) & 1, k + 1);   // prefetch overlaps compute
        const unsigned short* sb = smem[k & 1];
        f16x8 bf[4];
        #pragma unroll
        for (int ct = 0; ct < 4; ct++)
            bf[ct] = *(const f16x8*)&sb[(2 * RTB + cl0 + ct) * 512 + lane * 8];
        #pragma unroll
        for (int rt = 0; rt < RT; rt++) {
            f16x8 hi = *(const f16x8*)&sb[(rl0 + rt) * 512 + lane * 8];
            f16x8 lo = *(const f16x8*)&sb[(RTB + rl0 + rt) * 512 + lane * 8];
            #pragma unroll
            for (int ct = 0; ct < 4; ct++) {
                acc[rt][ct] = __builtin_amdgcn_mfma_f32_16x16x32_f16(lo, bf[ct], acc[rt][ct], 0, 0, 0);
                acc[rt][ct] = __builtin_amdgcn_mfma_f32_16x16x32_f16(hi, bf[ct], acc[rt][ct], 0, 0, 0);
            }
        }
        __syncthreads();   // drains prefetch vmcnt + guards buffer reuse
    }

    int quad = lane >> 4, l15 = lane & 15;
    float lmax = 0.f;
    #pragma unroll
    for (int rt = 0; rt < RT; rt++) {
        #pragma unroll
        for (int r = 0; r < 4; r++) {
            int row = (rtg0 + rl0 + rt) * 16 + quad * 4 + r;
            #pragma unroll
            for (int ct = 0; ct < 4; ct++) {
                int col = (ctg0 + cl0 + ct) * 16 + l15;
                float v = __fmul_rn(__fadd_rn(acc[rt][ct][r], bi[col]), bsf);
                lmax = fmaxf(lmax, fabsf(v));
                out[row * 384 + col] = v;
            }
        }
    }
    if (QKV) {
        #pragma unroll
        for (int off = 32; off; off >>= 1) lmax = fmaxf(lmax, __shfl_xor(lmax, off, 64));
        int hd = (cb >> 6) + (w >> 1);   // wave's 64 cols = one head
        if (lane == 0)
            atomicMax((unsigned int*)&ws_mut[16 + mat * 6 + hd], __float_as_uint(lmax));
    } else {
        if (mtile == 0 && nt == 0 && tid == 0) out[NE] = bsf;   // out_sf
    }
}

__global__ void k_scales(float* ws) {
    int h = threadIdx.x;
    if (h >= 6) return;
    const unsigned* wu = (const unsigned*)ws;
    float qsf = fmaxf(__uint_as_float(wu[16 + 0 * 6 + h]), 1e-8f) / 127.0f;
    float ksf = fmaxf(__uint_as_float(wu[16 + 1 * 6 + h]), 1e-8f) / 127.0f;
    float vsf = fmaxf(__uint_as_float(wu[16 + 2 * 6 + h]), 1e-8f) / 127.0f;
    float sf = __fmul_rn(ksf, qsf);
    const float X0f = -0.6931f;
    const float C0f = 0.35815147f;
    const float C1f = (float)(0.96963238 / 0.35815147);
    const float C2f = (float)(1.0 / 0.35815147);
    float x0i   = floorf(X0f / sf);
    float bpoly = floorf(C1f / sf);
    float sfsq  = __fmul_rn(sf, sf);
    float cint  = floorf(C2f / sfsq);
    float psf   = __fmul_rn(C0f, sfsq);
    float expsf = psf / 1073741824.0f;
    float rawmax = __fmul_rn(cint, 1073741824.0f);
    float s16 = fmaxf(__fmul_rn(rawmax, expsf), 1e-8f) / 32767.0f;
    float thirty = __fmul_rn(30.0f, x0i);
    ws[40+h]=qsf; ws[46+h]=ksf; ws[52+h]=vsf; ws[64+h]=sf; ws[70+h]=x0i;
    ws[76+h]=bpoly; ws[82+h]=cint; ws[88+h]=expsf; ws[94+h]=s16; ws[100+h]=thirty;
}

__device__ __forceinline__ unsigned short f16bits(float x) {
    _Float16 h = (_Float16)x;
    unsigned short u;
    __builtin_memcpy(&u, &h, 2);
    return u;
}

// quantize q/k -> int8 row-major; v -> f16 in B-fragment-swizzled order
__global__ __launch_bounds__(256) void k_prequant(const float* __restrict__ qb,
                                                  const float* __restrict__ kb,
                                                  const float* __restrict__ vb,
                                                  const float* __restrict__ ws,
                                                  char* __restrict__ q8,
                                                  char* __restrict__ k8,
                                                  unsigned short* __restrict__ vf) {
    int sec = blockIdx.x / 3072;
    int id = (blockIdx.x % 3072) * 256 + threadIdx.x;
    if (sec < 2) {
        const float* src = sec ? kb : qb;
        const float* sfb = ws + (sec ? 46 : 40);
        int row = id / 96, c4 = (id % 96) * 4;
        float s = sfb[c4 >> 6];
        float4 v = *(const float4*)&src[row * 384 + c4];
        int a0 = (int)fminf(fmaxf(rintf(v.x / s), -128.f), 127.f);
        int a1 = (int)fminf(fmaxf(rintf(v.y / s), -128.f), 127.f);
        int a2 = (int)fminf(fmaxf(rintf(v.z / s), -128.f), 127.f);
        int a3 = (int)fminf(fmaxf(rintf(v.w / s), -128.f), 127.f);
        unsigned pk = (unsigned)(a0 & 255) | ((unsigned)(a1 & 255) << 8) |
                      ((unsigned)(a2 & 255) << 16) | ((unsigned)(a3 & 255) << 24);
        ((unsigned*)(sec ? k8 : q8))[id] = pk;
    } else {
        int d = id & 63;
        int rest = id >> 6;
        int kvg = rest & 63;
        int bh = rest >> 6;
        int b = bh / 6, h = bh - (bh / 6) * 6;
        float s = ws[52 + h];
        int kv0 = kvg * 4;
        unsigned pk01, pk23;
        {
            float v0 = vb[(b * 256 + kv0 + 0) * 384 + h * 64 + d];
            float v1 = vb[(b * 256 + kv0 + 1) * 384 + h * 64 + d];
            float v2 = vb[(b * 256 + kv0 + 2) * 384 + h * 64 + d];
            float v3 = vb[(b * 256 + kv0 + 3) * 384 + h * 64 + d];
            unsigned short u0 = f16bits(fminf(fmaxf(rintf(v0 / s), -128.f), 127.f));
            unsigned short u1 = f16bits(fminf(fmaxf(rintf(v1 / s), -128.f), 127.f));
            unsigned short u2 = f16bits(fminf(fmaxf(rintf(v2 / s), -128.f), 127.f));
            unsigned short u3 = f16bits(fminf(fmaxf(rintf(v3 / s), -128.f), 127.f));
            pk01 = (unsigned)u0 | ((unsigned)u1 << 16);
            pk23 = (unsigned)u2 | ((unsigned)u3 << 16);
        }
        int c = kv0 >> 5, quad = (kv0 >> 3) & 3, j0 = kv0 & 7;
        int base = ((bh * 8 + c) * 4 + (d >> 4)) * 512 + (quad * 16 + (d & 15)) * 8 + j0;
        uint2 pk = make_uint2(pk01, pk23);
        *(uint2*)&vf[base] = pk;
    }
}

// fused MFMA attention; epilogue writes hi/lo f16 planes (A-fragment order)
__global__ __launch_bounds__(256) void k_attn(const char* __restrict__ q8,
                                              const char* __restrict__ k8,
                                              const unsigned short* __restrict__ vf,
                                              const float* __restrict__ ws,
                                              unsigned short* __restrict__ abhi,
                                              unsigned short* __restrict__ ablo) {
    __shared__ _Float16 pS[4][64][8];
    int qt = blockIdx.x & 3, bh = blockIdx.x >> 2;
    int b = bh / 6, h = bh - (bh / 6) * 6;
    float qsf = ws[40+h], ksf = ws[46+h], vsf = ws[52+h];
    float sf = ws[64+h], x0i = ws[70+h], bpoly = ws[76+h], cint = ws[82+h];
    float expsf = ws[88+h], s16 = ws[94+h], thirty = ws[100+h];

    int tid = threadIdx.x, w = tid >> 6, lane = tid & 63;
    int quad = lane >> 4, l15 = lane & 15;
    int strip0 = qt * 64 + w * 16;
    int ntiles = (strip0 >> 4) + 1;

    const i32x4 afrag = *(const i32x4*)(q8 + (b * 256 + strip0 + l15) * 384 + h * 64 + quad * 16);

    f32x4 xi[16];
    i32x4 zero4 = {0, 0, 0, 0};
    #pragma unroll
    for (int ct = 0; ct < 16; ct++) {
        if (ct < ntiles) {
            i32x4 bfrag = *(const i32x4*)(k8 + (b * 256 + ct * 16 + l15) * 384 + h * 64 + quad * 16);
            i32x4 c = __builtin_amdgcn_mfma_i32_16x16x64_i8(afrag, bfrag, zero4, 0, 0, 0);
            #pragma unroll
            for (int r = 0; r < 4; r++) {
                float wei = __fmul_rn(__fmul_rn(__fmul_rn((float)c[r], qsf), ksf), 0.125f);
                xi[ct][r] = wei / sf;
            }
        }
    }

    float NI = -__builtin_inff();
    f32x4 m = {NI, NI, NI, NI};
    #pragma unroll
    for (int ct = 0; ct < 16; ct++) {
        if (ct < ntiles) {
            bool last = (ct == ntiles - 1);
            #pragma unroll
            for (int r = 0; r < 4; r++)
                if (!last || (l15 <= quad * 4 + r)) m[r] = fmaxf(m[r], xi[ct][r]);
        }
    }
    #pragma unroll
    for (int o = 8; o; o >>= 1) {
        m.x = fmaxf(m.x, __shfl_xor(m.x, o));
        m.y = fmaxf(m.y, __shfl_xor(m.y, o));
        m.z = fmaxf(m.z, __shfl_xor(m.z, o));
        m.w = fmaxf(m.w, __shfl_xor(m.w, o));
    }

    f32x4 sum = {0.f, 0.f, 0.f, 0.f};
    #pragma unroll
    for (int ct = 0; ct < 16; ct++) {
        if (ct < ntiles) {
            bool last = (ct == ntiles - 1);
            #pragma unroll
            for (int r = 0; r < 4; r++) {
                float ei = 0.f;
                if (!last || (l15 <= quad * 4 + r)) {
                    float xsv = fmaxf(__fsub_rn(xi[ct][r], m[r]), thirty);
                    float qf = floorf(xsv / x0i);
                    float rr = __fsub_rn(xsv, __fmul_rn(x0i, qf));
                    float z = __fadd_rn(__fmul_rn(__fadd_rn(rr, bpoly), rr), cint);
                    float p2 = ldexpf(1.0f, 30 - (int)qf);
                    float eraw = fmaxf(floorf(__fmul_rn(z, p2)), 0.0f);
                    float esc = __fmul_rn(eraw, expsf);
                    float q16 = fminf(fmaxf(rintf(esc / s16), -32768.f), 32767.f);
                    float e = __fmul_rn(q16, s16);
                    ei = e / s16;
                }
                xi[ct][r] = ei;
                sum[r] += ei;
            }
        }
    }
    #pragma unroll
    for (int o = 8; o; o >>= 1) {
        sum.x += __shfl_xor(sum.x, o);
        sum.y += __shfl_xor(sum.y, o);
        sum.z += __shfl_xor(sum.z, o);
        sum.w += __shfl_xor(sum.w, o);
    }
    f32x4 fac;
    #pragma unroll
    for (int r = 0; r < 4; r++) fac[r] = floorf(4294967296.0f / sum[r]);

    #pragma unroll
    for (int ct = 0; ct < 16; ct++) {
        #pragma unroll
        for (int r = 0; r < 4; r++) {
            if (ct < ntiles)
                xi[ct][r] = floorf(__fmul_rn(__fmul_rn(xi[ct][r], fac[r]), 5.9604644775390625e-08f));
            else
                xi[ct][r] = 0.f;
        }
    }

    f32x4 o[4] = {};
    int nch = (ntiles + 1) >> 1;
    #pragma unroll
    for (int c = 0; c < 8; c++) {
        if (c < nch) {
            #pragma unroll
            for (int t2 = 0; t2 < 2; t2++) {
                int qd = t2 * 2 + (l15 >> 3);
                #pragma unroll
                for (int r = 0; r < 4; r++)
                    pS[w][qd * 16 + quad * 4 + r][l15 & 7] = (_Float16)xi[2 * c + t2][r];
            }
            f16x8 pa = *(f16x8*)&pS[w][lane][0];
            int vbase = ((bh * 8 + c) * 4) * 512 + lane * 8;
            #pragma unroll
            for (int cc = 0; cc < 4; cc++) {
                f16x8 vbf = *(const f16x8*)&vf[vbase + cc * 512];
                o[cc] = __builtin_amdgcn_mfma_f32_16x16x32_f16(pa, vbf, o[cc], 0, 0, 0);
            }
        }
    }

    // epilogue: out = ipv*vsf/256, split to f16 hi/lo planes in A-frag order
    int rowt12 = ((b * 256 + strip0) >> 4) * 12;
    #pragma unroll
    for (int cc = 0; cc < 4; cc++) {
        int fb = (rowt12 + h * 2 + (cc >> 1)) * 512;
        int sub = ((cc & 1) * 2 + (l15 >> 3)) * 16;
        #pragma unroll
        for (int r = 0; r < 4; r++) {
            float v = __fmul_rn(__fmul_rn(o[cc][r], vsf), 0.00390625f);
            _Float16 hh = (_Float16)v;
            float hf = (float)hh;
            _Float16 ll = (_Float16)__fsub_rn(v, hf);
            unsigned short hbb, lbb;
            __builtin_memcpy(&hbb, &hh, 2);
            __builtin_memcpy(&lbb, &ll, 2);
            int idx = fb + (sub + quad * 4 + r) * 8 + (l15 & 7);
            abhi[idx] = hbb;
            ablo[idx] = lbb;
        }
    }
}

extern "C" void kernel_launch(void* const* d_in, const int* in_sizes, int n_in,
                              void* d_out, int out_size, void* d_ws, size_t ws_size,
                              hipStream_t stream) {
    const float* x   = (const float*)d_in[0];
    const float* xsf = (const float*)d_in[1];
    const float* Wq  = (const float*)d_in[2];
    const float* bq  = (const float*)d_in[3];
    const float* Wk  = (const float*)d_in[4];
    const float* bk  = (const float*)d_in[5];
    const float* Wv  = (const float*)d_in[6];
    const float* bv  = (const float*)d_in[7];
    const float* Wp  = (const float*)d_in[8];
    const float* bp  = (const float*)d_in[9];
    float* ws  = (float*)d_ws;
    float* out = (float*)d_out;
    float* qkv = ws + WS_QBUF;

    unsigned short* xhi = (unsigned short*)(ws + WS_C8);
    unsigned short* xlo = xhi + NE;
    char*  q8  = (char*)(ws + WS_C8);
    char*  k8  = q8 + NE;
    unsigned short* vfp = (unsigned short*)(k8 + NE);
    unsigned short* abhi = (unsigned short*)(ws + WS_QBUF + NE);  // dead k-region
    unsigned short* ablo = abhi + NE;

    k_init<<<1, 256, 0, stream>>>(ws);
    k_wmax<<<144, 256, 0, stream>>>(Wq, Wk, Wv, Wp, ws);
    k_wquant<<<577, 256, 0, stream>>>(Wq, Wk, Wv, Wp, bq, bk, bv, bp, xsf, ws);
    k_xsplit<<<3072, 256, 0, stream>>>(x, xsf, xhi, xlo);
    k_gemm_lds<8, true><<<dim3(64, 9), 256, 0, stream>>>(xhi, xlo, ws, qkv, ws);
    k_scales<<<1, 64, 0, stream>>>(ws);
    k_prequant<<<9216, 256, 0, stream>>>(qkv, qkv + NE, qkv + 2 * NE, ws, q8, k8, vfp);
    k_attn<<<768, 256, 0, stream>>>(q8, k8, vfp, ws, abhi, ablo);
    k_gemm_lds<4, false><<<dim3(128, 3), 256, 0, stream>>>(abhi, ablo, ws, out, ws);
}